// Round 5
// baseline (1460.295 us; speedup 1.0000x reference)
//
#include <hip/hip_runtime.h>
#include <hip/hip_bf16.h>

typedef __attribute__((ext_vector_type(8))) short short8;
typedef __attribute__((ext_vector_type(4))) float float4v;
typedef unsigned short ushort_t;

#define BB 512
#define SS 512
#define EE 20
#define H1C 30
#define H2C 50
#define NTC 45

// raw barrier: order LDS only; leave global loads in flight (no vmcnt drain)
#define BAR() asm volatile("s_waitcnt lgkmcnt(0)\n\ts_barrier" ::: "memory")
// in-wave fence: compiler memory fence + LDS drain. Required for cross-lane LDS
// reuse without a barrier: the h-write (lane A) and next-step read (lane B) have
// NO same-thread alias, so without this the compiler may hoist the read above
// the write (this was round-4's 0.039 absmax bug).
#define WFENCE() asm volatile("s_waitcnt lgkmcnt(0)" ::: "memory")

#if __has_builtin(__builtin_amdgcn_exp2f)
#define EXP2(x) __builtin_amdgcn_exp2f(x)
#else
#define EXP2(x) exp2f(x)
#endif
#if __has_builtin(__builtin_amdgcn_rcpf)
#define RCPF(x) __builtin_amdgcn_rcpf(x)
#else
#define RCPF(x) (1.0f / (x))
#endif

#define LOG2E 1.4426950408889634f

// R0 activation helpers (lstm2 path, unchanged numerics)
__device__ __forceinline__ float sigf(float v) {
    return RCPF(1.0f + EXP2(-1.4426950408889634f * v));
}
__device__ __forceinline__ float tanh_(float v) {
    return 2.0f * RCPF(1.0f + EXP2(-2.8853900817779268f * v)) - 1.0f;
}

// lstm1 activation: gates pre-scaled by LOG2E (i,f,o) / 2*LOG2E (g) in the weights.
// Paired reciprocals: 5 exp2 + 3 rcp per output. (Proven numerics: round 3 passed.)
__device__ __forceinline__ float lstm_act(float gi, float gf, float gg, float go, float& c) {
    gi = fmaxf(gi, -30.f); gf = fmaxf(gf, -30.f);
    gg = fmaxf(gg, -30.f); go = fmaxf(go, -30.f);
    float di = 1.f + EXP2(-gi), df = 1.f + EXP2(-gf);
    float dg = 1.f + EXP2(-gg), dO = 1.f + EXP2(-go);
    float r1 = RCPF(di * df), r2 = RCPF(dg * dO);
    float si = df * r1, sf = di * r1;             // sigmoid(i), sigmoid(f)
    float tg = 2.f * (dO * r2) - 1.f;             // tanh(g)   (g pre-scaled 2x)
    float so = dg * r2;                           // sigmoid(o)
    float cc = sf * c + si * tg;
    c = cc;
    float e = EXP2(-2.8853900817779268f * cc);    // tanh(c)
    return so * (2.f * RCPF(1.f + e) - 1.f);
}

__device__ __forceinline__ ushort_t f2bf(float f) {           // RNE f32->bf16 bits
    unsigned u = __float_as_uint(f);
    unsigned r = u + 0x7FFFu + ((u >> 16) & 1u);
    return (ushort_t)(r >> 16);
}
__device__ __forceinline__ float bf2f(ushort_t s) { return __uint_as_float(((unsigned)s) << 16); }

__device__ __forceinline__ float ldG(const void* p, int i, int f32) {
    if (f32) return ((const float*)p)[i];
    return bf2f(((const ushort_t*)p)[i]);
}
__device__ __forceinline__ int ldTok(const void* x, int i, int x64) {
    const int* xi = (const int*)x;
    return x64 ? xi[2 * i] : xi[i];
}

// ---------------- dtype detector: flags[0]=is_f32, flags[1]=is_x_int64 ----------------
__global__ void detect_kernel(const void* bih, const void* x, int* flags) {
    if (threadIdx.x == 0 && blockIdx.x == 0) {
        const ushort_t* u = (const ushort_t*)bih;
        int isf = 0;
        for (int i = 0; i < 120; i++) {
            float v = fabsf(bf2f(u[i]));
            if (!(v < 16.0f)) isf = 1;
        }
        flags[0] = isf;
        const int* xi = (const int*)x;
        int orv = 0;
        for (int i = 1; i < 32; i += 2) orv |= xi[i];
        flags[1] = (orv == 0) ? 1 : 0;
    }
}

// raw emb-row chunk (defer cvt to LDS-write time). q=quad 0..2: elems q*8..(+8 or +4)
struct XR8 { uint4 a, b; };

__device__ __forceinline__ XR8 ldEmbChunk(const void* emb, int tok, int q, int f32v) {
    XR8 o;
    if (f32v) {
        const float* p = (const float*)emb + (size_t)tok * EE + q * 8;   // 16B aligned (80*tok + {0,32,64})
        o.a = *(const uint4*)p;
        o.b = (q < 2) ? *(const uint4*)(p + 4) : o.a;
    } else {
        const ushort_t* p = (const ushort_t*)emb + (size_t)tok * EE + q * 8;  // 8B aligned (40*tok + {0,16,32})
        uint2 lo = *(const uint2*)p;
        o.a.x = lo.x; o.a.y = lo.y; o.a.z = 0; o.a.w = 0;
        if (q < 2) { uint2 hi = *(const uint2*)(p + 4); o.a.z = hi.x; o.a.w = hi.y; }
        o.b = o.a;
    }
    return o;
}
__device__ __forceinline__ void writeXC(ushort_t* dst, const XR8& x, int q, int f32v) {
    if (f32v) {
        if (q < 2) {
            short8 s;
            s[0] = (short)f2bf(__uint_as_float(x.a.x)); s[1] = (short)f2bf(__uint_as_float(x.a.y));
            s[2] = (short)f2bf(__uint_as_float(x.a.z)); s[3] = (short)f2bf(__uint_as_float(x.a.w));
            s[4] = (short)f2bf(__uint_as_float(x.b.x)); s[5] = (short)f2bf(__uint_as_float(x.b.y));
            s[6] = (short)f2bf(__uint_as_float(x.b.z)); s[7] = (short)f2bf(__uint_as_float(x.b.w));
            *(short8*)dst = s;
        } else {
            ushort4 u4;
            u4.x = f2bf(__uint_as_float(x.a.x)); u4.y = f2bf(__uint_as_float(x.a.y));
            u4.z = f2bf(__uint_as_float(x.a.z)); u4.w = f2bf(__uint_as_float(x.a.w));
            *(ushort4*)dst = u4;
        }
    } else {
        if (q < 2) *(uint4*)dst = x.a;                 // already bf16 bits
        else { uint2 t2; t2.x = x.a.x; t2.y = x.a.y; *(uint2*)dst = t2; }
    }
}

// =========================================================================================
// Layer 1 — barrier-free, ONE WAVE = one chain (dir, 16 batch rows). grid 64 x block 64:
// each chain on its own CU (chain is trans-unit-bound; packing chains per SIMD adds nothing).
// Swapped MFMA: A = W (regs, hi/lo, 32 short8 = 128 VGPR), B = [x|1|h] wave-private LDS
// tile Bf[16 m][72 k] (144B stride). K: x 0..19, bias k=20 (B=1.0), h k=24+quad*8+u
// holding nn=u*4+quad, zero pads elsewhere.
// Gate interleave n = nn*4+g  =>  acc[u] regs r=0..3 are gates i,f,g,o of (m=li,
// nn=u*4+quad): activations consume MFMA output directly, zero exchange, no barrier.
// Cross-lane LDS h-reuse ordered by WFENCE() at each step top (round-4 bug fix).
// hs1 column order: col c = quad*8+u  <->  nn=(c&7)*4+(c>>3)  (lstm2 weight map matches).
// =========================================================================================
__global__ __launch_bounds__(64) void lstm1_kernel(
    const void* __restrict__ x,
    const void* __restrict__ emb_f, const void* __restrict__ emb_b,
    const void* __restrict__ h0_f, const void* __restrict__ c0_f,
    const void* __restrict__ Wih_f, const void* __restrict__ Whh_f,
    const void* __restrict__ bih_f, const void* __restrict__ bhh_f,
    const void* __restrict__ h0_b, const void* __restrict__ c0_b,
    const void* __restrict__ Wih_b, const void* __restrict__ Whh_b,
    const void* __restrict__ bih_b, const void* __restrict__ bhh_b,
    ushort_t* __restrict__ hsf, ushort_t* __restrict__ hsb,
    const int* __restrict__ flags)
{
    const int f32v = flags[0], x64 = flags[1];
    const int lane = threadIdx.x & 63, li = lane & 15, quad = lane >> 4;
    const int cg = blockIdx.x, dir = cg >> 5, j0 = (cg & 31) << 4;

    const void* emb = dir ? emb_b : emb_f;
    const void* h0  = dir ? h0_b  : h0_f;
    const void* c0  = dir ? c0_b  : c0_f;
    const void* Wih = dir ? Wih_b : Wih_f;
    const void* Whh = dir ? Whh_b : Whh_f;
    const void* bih = dir ? bih_b : bih_f;
    const void* bhh = dir ? bhh_b : bhh_f;
    ushort_t* hs = dir ? hsb : hsf;

    __shared__ __align__(16) ushort_t B[16][72];       // [m][k] tile, 144B stride

    for (int i = lane; i < 16 * 72; i += 64) ((ushort_t*)B)[i] = 0;
    if (quad == 0) B[li][20] = 0x3F80;                 // bias slot: constant 1.0

    // ---- weights in regs: A-frag lane holds W[n = u*16+li][k = quad*8+j] ----
    short8 whi[8][2], wlo[8][2];
    #pragma unroll
    for (int u = 0; u < 8; u++) {
        const int n = u * 16 + li;
        const int nn = n >> 2, g = n & 3;
        const bool nok = nn < H1C;
        const float sc = (g == 2) ? 2.0f * LOG2E : LOG2E;
        #pragma unroll
        for (int kt = 0; kt < 2; kt++) {
            short8 hi, lo;
            #pragma unroll
            for (int j = 0; j < 8; j++) {
                const int k = kt * 32 + quad * 8 + j;
                float w = 0.f;
                if (nok) {
                    if (k < EE) w = ldG(Wih, (g * H1C + nn) * EE + k, f32v);
                    else if (k == 20) w = ldG(bih, g * H1C + nn, f32v) + ldG(bhh, g * H1C + nn, f32v);
                    else if (k >= 24 && k < 56) {
                        const int qk = (k - 24) >> 3, uk = (k - 24) & 7, ns = uk * 4 + qk;
                        if (ns < H1C) w = ldG(Whh, (g * H1C + nn) * H1C + ns, f32v);
                    }
                }
                w *= sc;
                ushort_t b1 = f2bf(w);
                hi[j] = (short)b1;
                lo[j] = (short)f2bf(w - bf2f(b1));
            }
            whi[u][kt] = hi; wlo[u][kt] = lo;
        }
    }

    // ---- c0 / h0 init (lane (quad,li) owns nn = u*4+quad, m = li) ----
    float creg[8];
    {
        short8 hp;
        #pragma unroll
        for (int u = 0; u < 8; u++) {
            const int nn = u * 4 + quad;
            const bool ok = nn < H1C;
            creg[u] = ok ? ldG(c0, (j0 + li) * H1C + nn, f32v) : 0.f;
            hp[u] = ok ? (short)f2bf(ldG(h0, (j0 + li) * H1C + nn, f32v)) : (short)0;
        }
        *(short8*)&B[li][24 + quad * 8] = hp;
    }

    const int t0 = dir ? SS - 1 : 0, dt = dir ? -1 : 1;
    const int rbase = (j0 + li) * SS;
    const bool ldr = quad < 3;                          // x loader lanes (3 chunks/row)

    XR8 eA = {}, eB = {};
    int tA = 0, tB = 0;
    if (ldr) {
        int tk0 = ldTok(x, rbase + t0, x64);
        XR8 e0 = ldEmbChunk(emb, tk0, quad, f32v);
        writeXC(&B[li][quad * 8], e0, quad, f32v);      // x(0)
        int tk1 = ldTok(x, rbase + t0 + dt, x64);
        eA = ldEmbChunk(emb, tk1, quad, f32v);          // x(1) raw, consumed at it=0
        tA = ldTok(x, rbase + t0 + 2 * dt, x64);        // tok(2), consumed at it=0
    }

    auto step = [&](int it, XR8& ein, XR8& eout, int& tin, int& tout) {
        const int t = t0 + dt * it;
        WFENCE();   // order prior cross-lane LDS writes (h, x-stage, init) vs reads below
        short8 b0 = *(const short8*)&B[li][quad * 8];        // k 0..31
        short8 b1 = *(const short8*)&B[li][32 + quad * 8];   // k 32..63
        if (ldr) {
            if (it + 2 < SS) eout = ldEmbChunk(emb, tin, quad, f32v);          // x(t+2)
            if (it + 3 < SS) tout = ldTok(x, rbase + t0 + dt * (it + 3), x64); // tok(t+3)
        }
        float4v acc[8];
        #pragma unroll
        for (int u = 0; u < 8; u++) {
            float4v a; a[0] = 0.f; a[1] = 0.f; a[2] = 0.f; a[3] = 0.f;
            a = __builtin_amdgcn_mfma_f32_16x16x32_bf16(whi[u][0], b0, a, 0, 0, 0);
            a = __builtin_amdgcn_mfma_f32_16x16x32_bf16(wlo[u][0], b0, a, 0, 0, 0);
            a = __builtin_amdgcn_mfma_f32_16x16x32_bf16(whi[u][1], b1, a, 0, 0, 0);
            a = __builtin_amdgcn_mfma_f32_16x16x32_bf16(wlo[u][1], b1, a, 0, 0, 0);
            acc[u] = a;
        }
        // stage x(t+1) — same-thread alias with b0 read keeps program order
        if (ldr && it + 1 < SS) writeXC(&B[li][quad * 8], ein, quad, f32v);
        // activations: acc[u] = (i,f,g,o) of (m=li, nn=u*4+quad); pad nn -> exact h=0
        short8 hp;
        #pragma unroll
        for (int u = 0; u < 8; u++) {
            float hv = lstm_act(acc[u][0], acc[u][1], acc[u][2], acc[u][3], creg[u]);
            hp[u] = (short)f2bf(hv);
        }
        *(short8*)&B[li][24 + quad * 8] = hp;                                // h -> next step
        *(short8*)&hs[((size_t)(j0 + li) * SS + t) * 32 + quad * 8] = hp;    // hs1 out
    };
    for (int it = 0; it < SS; it += 2) { step(it, eA, eB, tA, tB); step(it + 1, eB, eA, tB, tA); }
}

// =========================================================================================
// Layer 2 — EXACT round-0 structure (known 399us): grid 64 (dir*32 + ablk), block 256.
// Only change vs round 0: Wih k<64 mapping follows lstm1's permuted hs1 column order
// (col c holds h-unit nn=(c&7)*4+(c>>3)).
// =========================================================================================
__global__ __launch_bounds__(256) void lstm2_kernel(
    const ushort_t* __restrict__ hs1f, const ushort_t* __restrict__ hs1b,
    const void* __restrict__ h0_f, const void* __restrict__ c0_f,
    const void* __restrict__ Wih_f, const void* __restrict__ Whh_f,
    const void* __restrict__ bih_f, const void* __restrict__ bhh_f,
    const void* __restrict__ h0_b, const void* __restrict__ c0_b,
    const void* __restrict__ Wih_b, const void* __restrict__ Whh_b,
    const void* __restrict__ bih_b, const void* __restrict__ bhh_b,
    ushort_t* __restrict__ hsf, ushort_t* __restrict__ hsb,
    const int* __restrict__ flags)
{
    const int f32v = flags[0];
    const int wg = blockIdx.x, dir = wg >> 5, cb = (wg & 31) << 4, tid = threadIdx.x;
    const int wave = tid >> 6, lane = tid & 63, li = lane & 15, quad = lane >> 4;

    const void* h0  = dir ? h0_b  : h0_f;
    const void* c0  = dir ? c0_b  : c0_f;
    const void* Wih = dir ? Wih_b : Wih_f;
    const void* Whh = dir ? Whh_b : Whh_f;
    const void* bih = dir ? bih_b : bih_f;
    const void* bhh = dir ? bhh_b : bhh_f;
    ushort_t* hs = dir ? hsb : hsf;

    __shared__ __align__(16) ushort_t Af[2][4][64][8];
    for (int idx = tid; idx < 2 * 4 * 64 * 8; idx += 256) ((ushort_t*)Af)[idx] = 0;

    const int n = wave * 16 + li;          // gate col / hidden idx (valid < 50)
    const bool nok = n < H2C;

    short8 bhi[4][4], blo[4][4];
    float bias_g[4];
    #pragma unroll
    for (int g = 0; g < 4; g++) {
        const int wrow = g * H2C + n;
        bias_g[g] = nok ? (ldG(bih, wrow, f32v) + ldG(bhh, wrow, f32v)) : 0.f;
        #pragma unroll
        for (int kt = 0; kt < 4; kt++) {
            short8 hi, lo;
            #pragma unroll
            for (int j = 0; j < 8; j++) {
                int k = kt * 32 + quad * 8 + j;
                float w = 0.f;
                if (nok) {
                    if (k < 32) {
                        const int c = k, nn2 = (c & 7) * 4 + (c >> 3);
                        if (nn2 < H1C) w = ldG(Wih, wrow * (2 * H1C) + nn2, f32v);
                    } else if (k < 64) {
                        const int c = k - 32, nn2 = (c & 7) * 4 + (c >> 3);
                        if (nn2 < H1C) w = ldG(Wih, wrow * (2 * H1C) + H1C + nn2, f32v);
                    } else if (k < 64 + H2C) {
                        w = ldG(Whh, wrow * H2C + (k - 64), f32v);
                    }
                }
                ushort_t h = f2bf(w);
                hi[j] = (short)h;
                lo[j] = (short)f2bf(w - bf2f(h));
            }
            bhi[g][kt] = hi; blo[g][kt] = lo;
        }
    }

    const int kh = 64 + n;                               // h k-slot 64..113
    const int khk = kh >> 5, khg = (kh & 31) >> 3, khj = kh & 7;
    const int lrow = tid >> 4, k0 = (tid & 15) * 4;      // x loader: all 256 threads
    const int t0 = dir ? SS - 1 : 0, dt = dir ? -1 : 1;

    // x value for step c, row a=cb+lrow, k-chunk k0 (0..60)
    auto loadX = [&](int c) -> ushort4 {
        const int a = cb + lrow;
        if (k0 < 32)
            return *(const ushort4*)&hs1f[((size_t)c * SS + a) * 32 + k0];
        else
            return *(const ushort4*)&hs1b[((size_t)c * SS + (SS - 1 - a)) * 32 + (k0 - 32)];
    };

    __syncthreads();   // Af zero visible

    float creg[4];
    #pragma unroll
    for (int r = 0; r < 4; r++) {
        const int m = quad * 4 + r;
        creg[r] = nok ? ldG(c0, (cb + m) * H2C + n, f32v) : 0.f;
        ushort_t hb0 = nok ? f2bf(ldG(h0, (cb + m) * H2C + n, f32v)) : (ushort_t)0;
        Af[0][khk][khg * 16 + m][khj] = hb0;
    }
    {
        ushort4 xi = loadX(t0);
        const int kg = (k0 & 31) >> 3, kt = k0 >> 5, jb = k0 & 7;
        Af[0][kt][kg * 16 + lrow][jb + 0] = xi.x;
        Af[0][kt][kg * 16 + lrow][jb + 1] = xi.y;
        Af[0][kt][kg * 16 + lrow][jb + 2] = xi.z;
        Af[0][kt][kg * 16 + lrow][jb + 3] = xi.w;
    }
    ushort4 xA = loadX(t0 + dt), xB;
    __syncthreads();   // Af[0] complete

    auto step = [&](int it, ushort4& xin, ushort4& xout) {
        const int c = t0 + dt * it;
        const int cur = it & 1, nxt = cur ^ 1;
        BAR();
        short8 af[4];
        #pragma unroll
        for (int kt = 0; kt < 4; kt++) af[kt] = *(const short8*)&Af[cur][kt][lane][0];
        if (it + 2 < SS) xout = loadX(c + 2 * dt);       // prefetch
        float4v acc[4];
        #pragma unroll
        for (int g = 0; g < 4; g++) {
            float4v a; a[0] = a[1] = a[2] = a[3] = bias_g[g];
            #pragma unroll
            for (int kt = 0; kt < 4; kt++) {
                a = __builtin_amdgcn_mfma_f32_16x16x32_bf16(af[kt], bhi[g][kt], a, 0, 0, 0);
                a = __builtin_amdgcn_mfma_f32_16x16x32_bf16(af[kt], blo[g][kt], a, 0, 0, 0);
            }
            acc[g] = a;
        }
        ushort_t hb[4];
        #pragma unroll
        for (int r = 0; r < 4; r++) {
            float gi = acc[0][r], gf = acc[1][r], gg = acc[2][r], go = acc[3][r];
            float cc = sigf(gf) * creg[r] + sigf(gi) * tanh_(gg);
            float h = sigf(go) * tanh_(cc);
            creg[r] = cc;
            hb[r] = nok ? f2bf(h) : (ushort_t)0;
        }
        // hs2T[c][n][a]: 4 consecutive batch rows -> one 8B store
        ushort4 h4; h4.x = hb[0]; h4.y = hb[1]; h4.z = hb[2]; h4.w = hb[3];
        *(ushort4*)&hs[((size_t)c * 64 + n) * SS + cb + quad * 4] = h4;
        if (it + 1 < SS) {
            #pragma unroll
            for (int r = 0; r < 4; r++) Af[nxt][khk][khg * 16 + quad * 4 + r][khj] = hb[r];
            const int kg = (k0 & 31) >> 3, kt = k0 >> 5, jb = k0 & 7;
            Af[nxt][kt][kg * 16 + lrow][jb + 0] = xin.x;
            Af[nxt][kt][kg * 16 + lrow][jb + 1] = xin.y;
            Af[nxt][kt][kg * 16 + lrow][jb + 2] = xin.z;
            Af[nxt][kt][kg * 16 + lrow][jb + 3] = xin.w;
        }
    };
    for (int it = 0; it < SS; it += 2) { step(it, xA, xB); step(it + 1, xB, xA); }
}

// =========================================================================================
// Final linear (MFMA GEMM) — exact round-0 code.
// =========================================================================================
__global__ __launch_bounds__(256) void lin_kernel(
    const ushort_t* __restrict__ hs2f, const ushort_t* __restrict__ hs2b,
    const void* __restrict__ lw, const void* __restrict__ lb,
    void* __restrict__ out, const int* __restrict__ flags)
{
    const int f32v = flags[0];
    const int tid = threadIdx.x, wave = tid >> 6, lane = tid & 63, li = lane & 15, quad = lane >> 4;

    __shared__ __align__(16) ushort_t Af[4][4][64][8];   // [wb][kt][kg*16+row][j]
    for (int idx = tid; idx < 4 * 4 * 64 * 8; idx += 256) ((ushort_t*)Af)[idx] = 0;

    short8 bhi[3][4], blo[3][4];
    float biasv[3];
    #pragma unroll
    for (int nt = 0; nt < 3; nt++) {
        const int nn = nt * 16 + li;
        const bool nok = nn < NTC;
        biasv[nt] = nok ? ldG(lb, nn, f32v) : 0.f;
        #pragma unroll
        for (int kt = 0; kt < 4; kt++) {
            short8 hi, lo;
            #pragma unroll
            for (int j = 0; j < 8; j++) {
                int k = kt * 32 + quad * 8 + j;
                float w = 0.f;
                if (nok) {
                    if (k < H2C) w = ldG(lw, nn * 100 + k, f32v);
                    else if (k >= 64 && k < 64 + H2C) w = ldG(lw, nn * 100 + 50 + (k - 64), f32v);
                }
                ushort_t h = f2bf(w);
                hi[j] = (short)h;
                lo[j] = (short)f2bf(w - bf2f(h));
            }
            bhi[nt][kt] = hi; blo[nt][kt] = lo;
        }
    }

    const int P0 = blockIdx.x * 64;
    const int i = P0 >> 9, j0 = P0 & 511;
    __syncthreads();   // Af zero
    // stage X: 100 valid k-rows x 64 pairs
    for (int idx = tid; idx < 100 * 32; idx += 256) {
        const int kk = idx >> 5, pj = (idx & 31) * 2;
        unsigned v;
        int k;
        if (kk < H2C) {
            v = *(const unsigned*)&hs2f[((size_t)i * 64 + kk) * SS + j0 + pj];
            k = kk;
        } else {
            v = *(const unsigned*)&hs2b[((size_t)(SS - 1 - i) * 64 + (kk - H2C)) * SS + j0 + pj];
            k = 64 + (kk - H2C);
        }
        const int kt = k >> 5, kg = (k & 31) >> 3, j = k & 7;
        Af[pj >> 4][kt][kg * 16 + (pj & 15)][j] = (ushort_t)(v & 0xFFFF);
        Af[pj >> 4][kt][kg * 16 + ((pj + 1) & 15)][j] = (ushort_t)(v >> 16);
    }
    __syncthreads();

    short8 af[4];
    #pragma unroll
    for (int kt = 0; kt < 4; kt++) af[kt] = *(const short8*)&Af[wave][kt][lane][0];
    #pragma unroll
    for (int nt = 0; nt < 3; nt++) {
        float4v a; a[0] = a[1] = a[2] = a[3] = biasv[nt];
        #pragma unroll
        for (int kt = 0; kt < 4; kt++) {
            a = __builtin_amdgcn_mfma_f32_16x16x32_bf16(af[kt], bhi[nt][kt], a, 0, 0, 0);
            a = __builtin_amdgcn_mfma_f32_16x16x32_bf16(af[kt], blo[nt][kt], a, 0, 0, 0);
        }
        const int nn = nt * 16 + li;
        if (nn < NTC) {
            #pragma unroll
            for (int reg = 0; reg < 4; reg++) {
                const int prow = wave * 16 + quad * 4 + reg;
                const size_t op = (size_t)(P0 + prow) * NTC + nn;
                if (f32v) ((float*)out)[op] = a[reg];
                else      ((ushort_t*)out)[op] = f2bf(a[reg]);
            }
        }
    }
}

extern "C" void kernel_launch(void* const* d_in, const int* in_sizes, int n_in,
                              void* d_out, int out_size, void* d_ws, size_t ws_size,
                              hipStream_t stream)
{
    const void* x      = d_in[0];
    const void* emb_f1 = d_in[1];
    const void* emb_b1 = d_in[2];
    const void* h0_f1  = d_in[3];
    const void* c0_f1  = d_in[4];
    const void* Wih_f1 = d_in[5];
    const void* Whh_f1 = d_in[6];
    const void* bih_f1 = d_in[7];
    const void* bhh_f1 = d_in[8];
    const void* h0_b1  = d_in[9];
    const void* c0_b1  = d_in[10];
    const void* Wih_b1 = d_in[11];
    const void* Whh_b1 = d_in[12];
    const void* bih_b1 = d_in[13];
    const void* bhh_b1 = d_in[14];
    const void* h0_f2  = d_in[15];
    const void* c0_f2  = d_in[16];
    const void* Wih_f2 = d_in[17];
    const void* Whh_f2 = d_in[18];
    const void* bih_f2 = d_in[19];
    const void* bhh_f2 = d_in[20];
    const void* h0_b2  = d_in[21];
    const void* c0_b2  = d_in[22];
    const void* Wih_b2 = d_in[23];
    const void* Whh_b2 = d_in[24];
    const void* bih_b2 = d_in[25];
    const void* bhh_b2 = d_in[26];
    const void* lin_w  = d_in[27];
    const void* lin_b  = d_in[28];

    // ws: flags(256B) | hs1Pf | hs1Pb ([512][512][32] bf16 each, 16.8MB)
    //                 | hs2fT | hs2bT ([512][64][512] bf16 each, 33.6MB)   total ~101MB
    int* flags = (int*)d_ws;
    ushort_t* hs1f = (ushort_t*)((char*)d_ws + 256);
    ushort_t* hs1b = hs1f + (size_t)BB * SS * 32;
    ushort_t* hs2f = hs1b + (size_t)BB * SS * 32;
    ushort_t* hs2b = hs2f + (size_t)SS * 64 * BB;

    detect_kernel<<<1, 64, 0, stream>>>(bih_f1, x, flags);
    lstm1_kernel<<<64, 64, 0, stream>>>(x, emb_f1, emb_b1,
        h0_f1, c0_f1, Wih_f1, Whh_f1, bih_f1, bhh_f1,
        h0_b1, c0_b1, Wih_b1, Whh_b1, bih_b1, bhh_b1, hs1f, hs1b, flags);
    lstm2_kernel<<<64, 256, 0, stream>>>(hs1f, hs1b,
        h0_f2, c0_f2, Wih_f2, Whh_f2, bih_f2, bhh_f2,
        h0_b2, c0_b2, Wih_b2, Whh_b2, bih_b2, bhh_b2, hs2f, hs2b, flags);
    lin_kernel<<<(BB * SS) / 64, 256, 0, stream>>>(hs2f, hs2b, lin_w, lin_b, d_out, flags);
}

// Round 6
// 1130.366 us; speedup vs baseline: 1.2919x; 1.2919x over previous
//
#include <hip/hip_runtime.h>
#include <hip/hip_bf16.h>

typedef __attribute__((ext_vector_type(8))) short short8;
typedef __attribute__((ext_vector_type(4))) float float4v;
typedef unsigned short ushort_t;

#define BB 512
#define SS 512
#define EE 20
#define H1C 30
#define H2C 50
#define NTC 45

// raw barrier: order LDS only; leave global loads in flight (no vmcnt drain)
#define BAR() asm volatile("s_waitcnt lgkmcnt(0)\n\ts_barrier" ::: "memory")
// in-wave fence: compiler memory fence + LDS drain (prologue ds_write -> loop ds_read)
#define WFENCE() asm volatile("s_waitcnt lgkmcnt(0)" ::: "memory")

#if __has_builtin(__builtin_amdgcn_exp2f)
#define EXP2(x) __builtin_amdgcn_exp2f(x)
#else
#define EXP2(x) exp2f(x)
#endif
#if __has_builtin(__builtin_amdgcn_rcpf)
#define RCPF(x) __builtin_amdgcn_rcpf(x)
#else
#define RCPF(x) (1.0f / (x))
#endif

#define LOG2E 1.4426950408889634f

// R0 activation helpers (lstm2 path, unchanged numerics)
__device__ __forceinline__ float sigf(float v) {
    return RCPF(1.0f + EXP2(-1.4426950408889634f * v));
}
__device__ __forceinline__ float tanh_(float v) {
    return 2.0f * RCPF(1.0f + EXP2(-2.8853900817779268f * v)) - 1.0f;
}

// lstm1 activation: gates pre-scaled by LOG2E (i,f,o) / 2*LOG2E (g) in the weights.
// Paired reciprocals: 5 exp2 + 3 rcp per output. (Proven numerics: rounds 3/5 passed.)
__device__ __forceinline__ float lstm_act(float gi, float gf, float gg, float go, float& c) {
    gi = fmaxf(gi, -30.f); gf = fmaxf(gf, -30.f);
    gg = fmaxf(gg, -30.f); go = fmaxf(go, -30.f);
    float di = 1.f + EXP2(-gi), df = 1.f + EXP2(-gf);
    float dg = 1.f + EXP2(-gg), dO = 1.f + EXP2(-go);
    float r1 = RCPF(di * df), r2 = RCPF(dg * dO);
    float si = df * r1, sf = di * r1;             // sigmoid(i), sigmoid(f)
    float tg = 2.f * (dO * r2) - 1.f;             // tanh(g)   (g pre-scaled 2x)
    float so = dg * r2;                           // sigmoid(o)
    float cc = sf * c + si * tg;
    c = cc;
    float e = EXP2(-2.8853900817779268f * cc);    // tanh(c)
    return so * (2.f * RCPF(1.f + e) - 1.f);
}

__device__ __forceinline__ ushort_t f2bf(float f) {           // RNE f32->bf16 bits
    unsigned u = __float_as_uint(f);
    unsigned r = u + 0x7FFFu + ((u >> 16) & 1u);
    return (ushort_t)(r >> 16);
}
__device__ __forceinline__ float bf2f(ushort_t s) { return __uint_as_float(((unsigned)s) << 16); }

__device__ __forceinline__ float ldG(const void* p, int i, int f32) {
    if (f32) return ((const float*)p)[i];
    return bf2f(((const ushort_t*)p)[i]);
}
__device__ __forceinline__ int ldTok(const void* x, int i, int x64) {
    const int* xi = (const int*)x;
    return x64 ? xi[2 * i] : xi[i];
}

// ---------------- dtype detector: flags[0]=is_f32, flags[1]=is_x_int64 ----------------
__global__ void detect_kernel(const void* bih, const void* x, int* flags) {
    if (threadIdx.x == 0 && blockIdx.x == 0) {
        const ushort_t* u = (const ushort_t*)bih;
        int isf = 0;
        for (int i = 0; i < 120; i++) {
            float v = fabsf(bf2f(u[i]));
            if (!(v < 16.0f)) isf = 1;
        }
        flags[0] = isf;
        const int* xi = (const int*)x;
        int orv = 0;
        for (int i = 1; i < 32; i += 2) orv |= xi[i];
        flags[1] = (orv == 0) ? 1 : 0;
    }
}

// raw emb chunk, per-lane: row = own token, elements quad*8..(+8). quad3: nothing.
struct XR8 { uint4 a, b; };

__device__ __forceinline__ XR8 ldEmbRawQ(const void* emb, int tok, int quad, int f32v) {
    XR8 o;
    o.a.x = 0; o.a.y = 0; o.a.z = 0; o.a.w = 0; o.b = o.a;
    if (quad < 3) {
        if (f32v) {
            const float* p = (const float*)emb + (size_t)tok * EE + quad * 8;  // 16B aligned
            o.a = *(const uint4*)p;
            if (quad < 2) o.b = *(const uint4*)(p + 4);
        } else {
            const ushort_t* p = (const ushort_t*)emb + (size_t)tok * EE + quad * 8;  // 8B aligned
            uint2 v0 = *(const uint2*)p;
            o.a.x = v0.x; o.a.y = v0.y;
            if (quad < 2) { uint2 v1 = *(const uint2*)(p + 4); o.a.z = v1.x; o.a.w = v1.y; }
        }
    }
    return o;
}

// build b0 B-frag register: k 0..19 = x, k 20 = 1.0 (bias slot), rest 0.
__device__ __forceinline__ short8 buildB0(const XR8& e, int quad, int f32v) {
    short8 bx;
    if (f32v) {
        bx[0] = (short)f2bf(__uint_as_float(e.a.x)); bx[1] = (short)f2bf(__uint_as_float(e.a.y));
        bx[2] = (short)f2bf(__uint_as_float(e.a.z)); bx[3] = (short)f2bf(__uint_as_float(e.a.w));
        bx[4] = (short)f2bf(__uint_as_float(e.b.x)); bx[5] = (short)f2bf(__uint_as_float(e.b.y));
        bx[6] = (short)f2bf(__uint_as_float(e.b.z)); bx[7] = (short)f2bf(__uint_as_float(e.b.w));
    } else {
        bx[0] = (short)(e.a.x & 0xFFFF); bx[1] = (short)(e.a.x >> 16);
        bx[2] = (short)(e.a.y & 0xFFFF); bx[3] = (short)(e.a.y >> 16);
        bx[4] = (short)(e.a.z & 0xFFFF); bx[5] = (short)(e.a.z >> 16);
        bx[6] = (short)(e.a.w & 0xFFFF); bx[7] = (short)(e.a.w >> 16);
    }
    if (quad == 2) { bx[4] = (short)0x3F80; bx[5] = 0; bx[6] = 0; bx[7] = 0; }
    if (quad == 3) { bx[0]=0;bx[1]=0;bx[2]=0;bx[3]=0;bx[4]=0;bx[5]=0;bx[6]=0;bx[7]=0; }
    return bx;
}

// =========================================================================================
// Layer 1 — REGISTER-RECURRENT. One wave = one chain (dir, 16 batch rows), grid 64 x 64.
// Swapped MFMA, gate interleave n = nn*4+g, 8 n-tiles (u): C layout gives lane (li,quad)
// all 4 gates of (m=li, nn=u*4+quad). h k-slot map nn = j*4+quad makes the B-frag h elem
// j=u on lane (li,quad) EXACTLY the value that lane computed: the packed short8 of acts
// IS the next step's B operand. h never touches LDS — zero sync on the recurrence.
// b0 = x(0..19)+bias(20): built per step in registers from per-lane emb loads (token
// table in read-only LDS). xacc pipelined one step ahead; emb prefetch ring depth 3.
// Per-gate accumulation order: x-hi, x-lo, h-hi, h-lo (round-5-proven numerics).
// hs1 col order: c = quad*8+u <-> nn=u*4+quad (lstm2 map nn=(c&7)*4+(c>>3), proven).
// =========================================================================================
__global__ __launch_bounds__(64, 1) void lstm1_kernel(
    const void* __restrict__ x,
    const void* __restrict__ emb_f, const void* __restrict__ emb_b,
    const void* __restrict__ h0_f, const void* __restrict__ c0_f,
    const void* __restrict__ Wih_f, const void* __restrict__ Whh_f,
    const void* __restrict__ bih_f, const void* __restrict__ bhh_f,
    const void* __restrict__ h0_b, const void* __restrict__ c0_b,
    const void* __restrict__ Wih_b, const void* __restrict__ Whh_b,
    const void* __restrict__ bih_b, const void* __restrict__ bhh_b,
    ushort_t* __restrict__ hsf, ushort_t* __restrict__ hsb,
    const int* __restrict__ flags)
{
    const int f32v = flags[0], x64 = flags[1];
    const int lane = threadIdx.x & 63, li = lane & 15, quad = lane >> 4;
    const int cg = blockIdx.x, dir = cg >> 5, j0 = (cg & 31) << 4;

    const void* emb = dir ? emb_b : emb_f;
    const void* h0  = dir ? h0_b  : h0_f;
    const void* c0  = dir ? c0_b  : c0_f;
    const void* Wih = dir ? Wih_b : Wih_f;
    const void* Whh = dir ? Whh_b : Whh_f;
    const void* bih = dir ? bih_b : bih_f;
    const void* bhh = dir ? bhh_b : bhh_f;
    ushort_t* hs = dir ? hsb : hsf;

    __shared__ int toks[16][SS];                       // 32KB, read-only in loop

    for (int idx = lane; idx < 16 * SS; idx += 64)
        toks[idx >> 9][idx & (SS - 1)] = ldTok(x, (j0 + (idx >> 9)) * SS + (idx & (SS - 1)), x64);

    // ---- weights in regs. A-frag (tile u): lane holds W[n=u*16+li][k].
    //      n -> nn = u*4+(li>>2), g = li&3. b0: k=quad*8+j. b1 elem j: nn_src=j*4+quad.
    const int gA = li & 3, nbase = li >> 2;
    const float sc = (gA == 2) ? 2.0f * LOG2E : LOG2E;
    short8 wxh[8], wxl[8], whh[8], whl[8];
    #pragma unroll
    for (int u = 0; u < 8; u++) {
        const int nn = u * 4 + nbase;
        const bool ok = nn < H1C;
        short8 xh, xl, hh, hl;
        #pragma unroll
        for (int j = 0; j < 8; j++) {
            const int k = quad * 8 + j;
            float wx = 0.f;
            if (ok) {
                if (k < EE) wx = ldG(Wih, (gA * H1C + nn) * EE + k, f32v);
                else if (k == 20) wx = ldG(bih, gA * H1C + nn, f32v) + ldG(bhh, gA * H1C + nn, f32v);
            }
            wx *= sc;
            ushort_t bx1 = f2bf(wx); xh[j] = (short)bx1; xl[j] = (short)f2bf(wx - bf2f(bx1));
            const int ns = j * 4 + quad;
            float wh = (ok && ns < H1C) ? sc * ldG(Whh, (gA * H1C + nn) * H1C + ns, f32v) : 0.f;
            ushort_t bh1 = f2bf(wh); hh[j] = (short)bh1; hl[j] = (short)f2bf(wh - bf2f(bh1));
        }
        wxh[u] = xh; wxl[u] = xl; whh[u] = hh; whl[u] = hl;
    }

    // ---- c0 / h0 (act/C layout: lane (li,quad) owns (m=li, nn=u*4+quad)) ----
    float creg[8];
    short8 b1;
    #pragma unroll
    for (int u = 0; u < 8; u++) {
        const int nn = u * 4 + quad;
        const bool ok = nn < H1C;
        creg[u] = ok ? ldG(c0, (j0 + li) * H1C + nn, f32v) : 0.f;
        b1[u] = ok ? (short)f2bf(ldG(h0, (j0 + li) * H1C + nn, f32v)) : (short)0;
    }

    const int t0 = dir ? SS - 1 : 0, dt = dir ? -1 : 1;

    WFENCE();   // toks table visible to own-wave ds_reads below

    // ---- prologue: b0(t0), xacc(t0); ring slots e1=emb(1), e2=emb(2); tok regs ----
    int tkA = toks[li][t0 + dt * 3];
    int tkB = toks[li][t0 + dt * 4];
    XR8 e0r, e1r, e2r, e3r;
    float4v xacc[8];
    {
        int tk0 = toks[li][t0];
        int tk1 = toks[li][t0 + dt];
        int tk2 = toks[li][t0 + dt * 2];
        XR8 ecur = ldEmbRawQ(emb, tk0, quad, f32v);
        e1r = ldEmbRawQ(emb, tk1, quad, f32v);
        e2r = ldEmbRawQ(emb, tk2, quad, f32v);
        e0r = ecur; e3r = ecur;                        // init (overwritten before read)
        short8 bx = buildB0(ecur, quad, f32v);
        #pragma unroll
        for (int u = 0; u < 8; u++) {
            float4v a; a[0] = 0.f; a[1] = 0.f; a[2] = 0.f; a[3] = 0.f;
            a = __builtin_amdgcn_mfma_f32_16x16x32_bf16(wxh[u], bx, a, 0, 0, 0);
            a = __builtin_amdgcn_mfma_f32_16x16x32_bf16(wxl[u], bx, a, 0, 0, 0);
            xacc[u] = a;
        }
    }

    auto step = [&](int it, XR8& cons, XR8& fill, int& tk) {
        const int t = t0 + dt * it;
        // on-path: gates(t) = xacc(t) + Whh_hi*h + Whh_lo*h   (h = b1, registers)
        float4v acc[8];
        #pragma unroll
        for (int u = 0; u < 8; u++) {
            float4v a = xacc[u];
            a = __builtin_amdgcn_mfma_f32_16x16x32_bf16(whh[u], b1, a, 0, 0, 0);
            a = __builtin_amdgcn_mfma_f32_16x16x32_bf16(whl[u], b1, a, 0, 0, 0);
            acc[u] = a;
        }
        // off-path: prefetch emb(t+3); refill tok (used 2 steps later); xacc(t+1)
        if (it + 3 < SS) fill = ldEmbRawQ(emb, tk, quad, f32v);
        {
            int ti = it + 5; if (ti > SS - 1) ti = SS - 1;
            tk = toks[li][t0 + dt * ti];
        }
        short8 bx = buildB0(cons, quad, f32v);               // emb(t+1), loaded 2 steps ago
        float4v xn[8];
        #pragma unroll
        for (int u = 0; u < 8; u++) {
            float4v a; a[0] = 0.f; a[1] = 0.f; a[2] = 0.f; a[3] = 0.f;
            a = __builtin_amdgcn_mfma_f32_16x16x32_bf16(wxh[u], bx, a, 0, 0, 0);
            a = __builtin_amdgcn_mfma_f32_16x16x32_bf16(wxl[u], bx, a, 0, 0, 0);
            xn[u] = a;
        }
        // act: acc[u] = (i,f,g,o) of (m=li, nn=u*4+quad); pack -> next h B-operand
        short8 hp;
        #pragma unroll
        for (int u = 0; u < 8; u++) {
            float hv = lstm_act(acc[u][0], acc[u][1], acc[u][2], acc[u][3], creg[u]);
            hp[u] = (short)f2bf(hv);
        }
        b1 = hp;                                             // REGISTER recurrence
        *(short8*)&hs[((size_t)(j0 + li) * SS + t) * 32 + quad * 8] = hp;
        #pragma unroll
        for (int u = 0; u < 8; u++) xacc[u] = xn[u];
    };
    for (int it = 0; it < SS; it += 4) {
        step(it,     e1r, e3r, tkA);
        step(it + 1, e2r, e0r, tkB);
        step(it + 2, e3r, e1r, tkA);
        step(it + 3, e0r, e2r, tkB);
    }
}

// =========================================================================================
// Layer 2 — EXACT round-5 code (passed; R0 structure ~399us; permuted Wih col map).
// =========================================================================================
__global__ __launch_bounds__(256) void lstm2_kernel(
    const ushort_t* __restrict__ hs1f, const ushort_t* __restrict__ hs1b,
    const void* __restrict__ h0_f, const void* __restrict__ c0_f,
    const void* __restrict__ Wih_f, const void* __restrict__ Whh_f,
    const void* __restrict__ bih_f, const void* __restrict__ bhh_f,
    const void* __restrict__ h0_b, const void* __restrict__ c0_b,
    const void* __restrict__ Wih_b, const void* __restrict__ Whh_b,
    const void* __restrict__ bih_b, const void* __restrict__ bhh_b,
    ushort_t* __restrict__ hsf, ushort_t* __restrict__ hsb,
    const int* __restrict__ flags)
{
    const int f32v = flags[0];
    const int wg = blockIdx.x, dir = wg >> 5, cb = (wg & 31) << 4, tid = threadIdx.x;
    const int wave = tid >> 6, lane = tid & 63, li = lane & 15, quad = lane >> 4;

    const void* h0  = dir ? h0_b  : h0_f;
    const void* c0  = dir ? c0_b  : c0_f;
    const void* Wih = dir ? Wih_b : Wih_f;
    const void* Whh = dir ? Whh_b : Whh_f;
    const void* bih = dir ? bih_b : bih_f;
    const void* bhh = dir ? bhh_b : bhh_f;
    ushort_t* hs = dir ? hsb : hsf;

    __shared__ __align__(16) ushort_t Af[2][4][64][8];
    for (int idx = tid; idx < 2 * 4 * 64 * 8; idx += 256) ((ushort_t*)Af)[idx] = 0;

    const int n = wave * 16 + li;          // gate col / hidden idx (valid < 50)
    const bool nok = n < H2C;

    short8 bhi[4][4], blo[4][4];
    float bias_g[4];
    #pragma unroll
    for (int g = 0; g < 4; g++) {
        const int wrow = g * H2C + n;
        bias_g[g] = nok ? (ldG(bih, wrow, f32v) + ldG(bhh, wrow, f32v)) : 0.f;
        #pragma unroll
        for (int kt = 0; kt < 4; kt++) {
            short8 hi, lo;
            #pragma unroll
            for (int j = 0; j < 8; j++) {
                int k = kt * 32 + quad * 8 + j;
                float w = 0.f;
                if (nok) {
                    if (k < 32) {
                        const int c = k, nn2 = (c & 7) * 4 + (c >> 3);
                        if (nn2 < H1C) w = ldG(Wih, wrow * (2 * H1C) + nn2, f32v);
                    } else if (k < 64) {
                        const int c = k - 32, nn2 = (c & 7) * 4 + (c >> 3);
                        if (nn2 < H1C) w = ldG(Wih, wrow * (2 * H1C) + H1C + nn2, f32v);
                    } else if (k < 64 + H2C) {
                        w = ldG(Whh, wrow * H2C + (k - 64), f32v);
                    }
                }
                ushort_t h = f2bf(w);
                hi[j] = (short)h;
                lo[j] = (short)f2bf(w - bf2f(h));
            }
            bhi[g][kt] = hi; blo[g][kt] = lo;
        }
    }

    const int kh = 64 + n;                               // h k-slot 64..113
    const int khk = kh >> 5, khg = (kh & 31) >> 3, khj = kh & 7;
    const int lrow = tid >> 4, k0 = (tid & 15) * 4;      // x loader: all 256 threads
    const int t0 = dir ? SS - 1 : 0, dt = dir ? -1 : 1;

    auto loadX = [&](int c) -> ushort4 {
        const int a = cb + lrow;
        if (k0 < 32)
            return *(const ushort4*)&hs1f[((size_t)c * SS + a) * 32 + k0];
        else
            return *(const ushort4*)&hs1b[((size_t)c * SS + (SS - 1 - a)) * 32 + (k0 - 32)];
    };

    __syncthreads();   // Af zero visible

    float creg[4];
    #pragma unroll
    for (int r = 0; r < 4; r++) {
        const int m = quad * 4 + r;
        creg[r] = nok ? ldG(c0, (cb + m) * H2C + n, f32v) : 0.f;
        ushort_t hb0 = nok ? f2bf(ldG(h0, (cb + m) * H2C + n, f32v)) : (ushort_t)0;
        Af[0][khk][khg * 16 + m][khj] = hb0;
    }
    {
        ushort4 xi = loadX(t0);
        const int kg = (k0 & 31) >> 3, kt = k0 >> 5, jb = k0 & 7;
        Af[0][kt][kg * 16 + lrow][jb + 0] = xi.x;
        Af[0][kt][kg * 16 + lrow][jb + 1] = xi.y;
        Af[0][kt][kg * 16 + lrow][jb + 2] = xi.z;
        Af[0][kt][kg * 16 + lrow][jb + 3] = xi.w;
    }
    ushort4 xA = loadX(t0 + dt), xB;
    __syncthreads();   // Af[0] complete

    auto step = [&](int it, ushort4& xin, ushort4& xout) {
        const int c = t0 + dt * it;
        const int cur = it & 1, nxt = cur ^ 1;
        BAR();
        short8 af[4];
        #pragma unroll
        for (int kt = 0; kt < 4; kt++) af[kt] = *(const short8*)&Af[cur][kt][lane][0];
        if (it + 2 < SS) xout = loadX(c + 2 * dt);       // prefetch
        float4v acc[4];
        #pragma unroll
        for (int g = 0; g < 4; g++) {
            float4v a; a[0] = a[1] = a[2] = a[3] = bias_g[g];
            #pragma unroll
            for (int kt = 0; kt < 4; kt++) {
                a = __builtin_amdgcn_mfma_f32_16x16x32_bf16(af[kt], bhi[g][kt], a, 0, 0, 0);
                a = __builtin_amdgcn_mfma_f32_16x16x32_bf16(af[kt], blo[g][kt], a, 0, 0, 0);
            }
            acc[g] = a;
        }
        ushort_t hb[4];
        #pragma unroll
        for (int r = 0; r < 4; r++) {
            float gi = acc[0][r], gf = acc[1][r], gg = acc[2][r], go = acc[3][r];
            float cc = sigf(gf) * creg[r] + sigf(gi) * tanh_(gg);
            float h = sigf(go) * tanh_(cc);
            creg[r] = cc;
            hb[r] = nok ? f2bf(h) : (ushort_t)0;
        }
        ushort4 h4; h4.x = hb[0]; h4.y = hb[1]; h4.z = hb[2]; h4.w = hb[3];
        *(ushort4*)&hs[((size_t)c * 64 + n) * SS + cb + quad * 4] = h4;
        if (it + 1 < SS) {
            #pragma unroll
            for (int r = 0; r < 4; r++) Af[nxt][khk][khg * 16 + quad * 4 + r][khj] = hb[r];
            const int kg = (k0 & 31) >> 3, kt = k0 >> 5, jb = k0 & 7;
            Af[nxt][kt][kg * 16 + lrow][jb + 0] = xin.x;
            Af[nxt][kt][kg * 16 + lrow][jb + 1] = xin.y;
            Af[nxt][kt][kg * 16 + lrow][jb + 2] = xin.z;
            Af[nxt][kt][kg * 16 + lrow][jb + 3] = xin.w;
        }
    };
    for (int it = 0; it < SS; it += 2) { step(it, xA, xB); step(it + 1, xB, xA); }
}

// =========================================================================================
// Final linear (MFMA GEMM) — exact round-0 code.
// =========================================================================================
__global__ __launch_bounds__(256) void lin_kernel(
    const ushort_t* __restrict__ hs2f, const ushort_t* __restrict__ hs2b,
    const void* __restrict__ lw, const void* __restrict__ lb,
    void* __restrict__ out, const int* __restrict__ flags)
{
    const int f32v = flags[0];
    const int tid = threadIdx.x, wave = tid >> 6, lane = tid & 63, li = lane & 15, quad = lane >> 4;

    __shared__ __align__(16) ushort_t Af[4][4][64][8];   // [wb][kt][kg*16+row][j]
    for (int idx = tid; idx < 4 * 4 * 64 * 8; idx += 256) ((ushort_t*)Af)[idx] = 0;

    short8 bhi[3][4], blo[3][4];
    float biasv[3];
    #pragma unroll
    for (int nt = 0; nt < 3; nt++) {
        const int nn = nt * 16 + li;
        const bool nok = nn < NTC;
        biasv[nt] = nok ? ldG(lb, nn, f32v) : 0.f;
        #pragma unroll
        for (int kt = 0; kt < 4; kt++) {
            short8 hi, lo;
            #pragma unroll
            for (int j = 0; j < 8; j++) {
                int k = kt * 32 + quad * 8 + j;
                float w = 0.f;
                if (nok) {
                    if (k < H2C) w = ldG(lw, nn * 100 + k, f32v);
                    else if (k >= 64 && k < 64 + H2C) w = ldG(lw, nn * 100 + 50 + (k - 64), f32v);
                }
                ushort_t h = f2bf(w);
                hi[j] = (short)h;
                lo[j] = (short)f2bf(w - bf2f(h));
            }
            bhi[nt][kt] = hi; blo[nt][kt] = lo;
        }
    }

    const int P0 = blockIdx.x * 64;
    const int i = P0 >> 9, j0 = P0 & 511;
    __syncthreads();   // Af zero
    for (int idx = tid; idx < 100 * 32; idx += 256) {
        const int kk = idx >> 5, pj = (idx & 31) * 2;
        unsigned v;
        int k;
        if (kk < H2C) {
            v = *(const unsigned*)&hs2f[((size_t)i * 64 + kk) * SS + j0 + pj];
            k = kk;
        } else {
            v = *(const unsigned*)&hs2b[((size_t)(SS - 1 - i) * 64 + (kk - H2C)) * SS + j0 + pj];
            k = 64 + (kk - H2C);
        }
        const int kt = k >> 5, kg = (k & 31) >> 3, j = k & 7;
        Af[pj >> 4][kt][kg * 16 + (pj & 15)][j] = (ushort_t)(v & 0xFFFF);
        Af[pj >> 4][kt][kg * 16 + ((pj + 1) & 15)][j] = (ushort_t)(v >> 16);
    }
    __syncthreads();

    short8 af[4];
    #pragma unroll
    for (int kt = 0; kt < 4; kt++) af[kt] = *(const short8*)&Af[wave][kt][lane][0];
    #pragma unroll
    for (int nt = 0; nt < 3; nt++) {
        float4v a; a[0] = a[1] = a[2] = a[3] = biasv[nt];
        #pragma unroll
        for (int kt = 0; kt < 4; kt++) {
            a = __builtin_amdgcn_mfma_f32_16x16x32_bf16(af[kt], bhi[nt][kt], a, 0, 0, 0);
            a = __builtin_amdgcn_mfma_f32_16x16x32_bf16(af[kt], blo[nt][kt], a, 0, 0, 0);
        }
        const int nn = nt * 16 + li;
        if (nn < NTC) {
            #pragma unroll
            for (int reg = 0; reg < 4; reg++) {
                const int prow = wave * 16 + quad * 4 + reg;
                const size_t op = (size_t)(P0 + prow) * NTC + nn;
                if (f32v) ((float*)out)[op] = a[reg];
                else      ((ushort_t*)out)[op] = f2bf(a[reg]);
            }
        }
    }
}

extern "C" void kernel_launch(void* const* d_in, const int* in_sizes, int n_in,
                              void* d_out, int out_size, void* d_ws, size_t ws_size,
                              hipStream_t stream)
{
    const void* x      = d_in[0];
    const void* emb_f1 = d_in[1];
    const void* emb_b1 = d_in[2];
    const void* h0_f1  = d_in[3];
    const void* c0_f1  = d_in[4];
    const void* Wih_f1 = d_in[5];
    const void* Whh_f1 = d_in[6];
    const void* bih_f1 = d_in[7];
    const void* bhh_f1 = d_in[8];
    const void* h0_b1  = d_in[9];
    const void* c0_b1  = d_in[10];
    const void* Wih_b1 = d_in[11];
    const void* Whh_b1 = d_in[12];
    const void* bih_b1 = d_in[13];
    const void* bhh_b1 = d_in[14];
    const void* h0_f2  = d_in[15];
    const void* c0_f2  = d_in[16];
    const void* Wih_f2 = d_in[17];
    const void* Whh_f2 = d_in[18];
    const void* bih_f2 = d_in[19];
    const void* bhh_f2 = d_in[20];
    const void* h0_b2  = d_in[21];
    const void* c0_b2  = d_in[22];
    const void* Wih_b2 = d_in[23];
    const void* Whh_b2 = d_in[24];
    const void* bih_b2 = d_in[25];
    const void* bhh_b2 = d_in[26];
    const void* lin_w  = d_in[27];
    const void* lin_b  = d_in[28];

    // ws: flags(256B) | hs1Pf | hs1Pb ([512][512][32] bf16 each, 16.8MB)
    //                 | hs2fT | hs2bT ([512][64][512] bf16 each, 33.6MB)   total ~101MB
    int* flags = (int*)d_ws;
    ushort_t* hs1f = (ushort_t*)((char*)d_ws + 256);
    ushort_t* hs1b = hs1f + (size_t)BB * SS * 32;
    ushort_t* hs2f = hs1b + (size_t)BB * SS * 32;
    ushort_t* hs2b = hs2f + (size_t)SS * 64 * BB;

    detect_kernel<<<1, 64, 0, stream>>>(bih_f1, x, flags);
    lstm1_kernel<<<64, 64, 0, stream>>>(x, emb_f1, emb_b1,
        h0_f1, c0_f1, Wih_f1, Whh_f1, bih_f1, bhh_f1,
        h0_b1, c0_b1, Wih_b1, Whh_b1, bih_b1, bhh_b1, hs1f, hs1b, flags);
    lstm2_kernel<<<64, 256, 0, stream>>>(hs1f, hs1b,
        h0_f2, c0_f2, Wih_f2, Whh_f2, bih_f2, bhh_f2,
        h0_b2, c0_b2, Wih_b2, Whh_b2, bih_b2, bhh_b2, hs2f, hs2b, flags);
    lin_kernel<<<(BB * SS) / 64, 256, 0, stream>>>(hs2f, hs2b, lin_w, lin_b, d_out, flags);
}